// Round 2
// baseline (81.487 us; speedup 1.0000x reference)
//
#include <hip/hip_runtime.h>
#include <math.h>

#define B_ 32
#define N_ 1024
#define H_ 768
#define A_ 8
#define TOPK_ 20
#define CH2_ 16   // att row-chunks per batch (64 rows each)
#define CH4_ 16   // h   row-chunks per batch (64 rows each)

__device__ __forceinline__ float wsum(float x) {
#pragma unroll
    for (int off = 32; off > 0; off >>= 1) x += __shfl_xor(x, off);
    return x;
}

// ---------------------------------------------------------------------------
// K1: top-20 indicators for a_idx/b_idx rows, Dv, De.  grid=B, block=1024.
// ---------------------------------------------------------------------------
__global__ __launch_bounds__(1024) void k1_ind(
    const float* __restrict__ att, const int* __restrict__ a_idx,
    const int* __restrict__ b_idx, const float* __restrict__ speak_all,
    float* __restrict__ aind, float* __restrict__ bind,
    float* __restrict__ Dv, float* __restrict__ De)
{
    const int b = blockIdx.x;
    const int tid = threadIdx.x;
    const int w = tid >> 6, lane = tid & 63;
    __shared__ float s_ind[2][N_];
    __shared__ float s_red[3][16];

    s_ind[0][tid] = 0.f;
    s_ind[1][tid] = 0.f;
    __syncthreads();

    // one wave per selected row: waves 0-7 -> a_idx, 8-15 -> b_idx
    const int which = w >> 3;
    const int r = w & 7;
    const int idx = which ? b_idx[b * A_ + r] : a_idx[b * A_ + r];
    if (idx != 0) {  // mask = (idx != 0)
        const float* row = att + ((size_t)b * N_ + idx) * N_;
        float v[16];
#pragma unroll
        for (int k = 0; k < 16; ++k) v[k] = row[(k << 6) + lane];
        float* dst = s_ind[which];
        for (int t = 0; t < TOPK_; ++t) {
            float bv = v[0]; int bk = 0;
#pragma unroll
            for (int k = 1; k < 16; ++k)
                if (v[k] > bv) { bv = v[k]; bk = k; }   // strict > : lower col wins ties
            int bc = (bk << 6) + lane;
#pragma unroll
            for (int off = 32; off > 0; off >>= 1) {
                float ov = __shfl_xor(bv, off);
                int oc = __shfl_xor(bc, off);
                if (ov > bv || (ov == bv && oc < bc)) { bv = ov; bc = oc; }
            }
            if (lane == 0) dst[bc] = 1.f;      // benign same-value races across waves
            if (lane == (bc & 63)) v[bc >> 6] = -INFINITY;
        }
    }
    __syncthreads();

    const float sa = s_ind[0][tid], sb = s_ind[1][tid];
    const float ss = speak_all[(size_t)b * 3 * N_ + tid];
    aind[b * N_ + tid] = sa;
    bind[b * N_ + tid] = sb;
    Dv[b * N_ + tid] = 1.f / sqrtf(sa + sb + ss + 1.f);

    float p[3] = {sa, sb, ss};
#pragma unroll
    for (int e = 0; e < 3; ++e) {
        float x = wsum(p[e]);
        if (lane == 0) s_red[e][w] = x;
    }
    __syncthreads();
    if (tid < 3) {
        float s = 0.f;
        for (int i = 0; i < 16; ++i) s += s_red[tid][i];
        De[b * 3 + tid] = 1.f / sqrtf(s);
    }
}

// ---------------------------------------------------------------------------
// K2: partial Hyper.  grid=(CH2_, B), block=256.  Each block streams 64 FULL
// contiguous att rows (4KB each), skipping inactive rows via a block-uniform
// compacted list (no divergence, branch-free hot loop).  Thread t owns cols
// [4t,4t+4).  Writes partial[b][c][3][N].
// ---------------------------------------------------------------------------
__global__ __launch_bounds__(256) void k2_part(
    const float* __restrict__ att, const float* __restrict__ aind,
    const float* __restrict__ bind, const float* __restrict__ speak_all,
    float* __restrict__ Hpart)
{
    const int b = blockIdx.y, c = blockIdx.x;
    const int n0 = c * 64;
    const int t = threadIdx.x;
    __shared__ float sw[3][64];
    __shared__ int rows[64];
    __shared__ int s_nr;

    if (t < 192) {
        const int e = t >> 6, r = t & 63, n = n0 + r;
        float v;
        if (e == 0)      v = aind[b * N_ + n];
        else if (e == 1) v = bind[b * N_ + n];
        else             v = speak_all[(size_t)b * 3 * N_ + n];
        sw[e][r] = v;
    }
    __syncthreads();
    if (t < 64) {   // wave 0 only
        const bool act = (sw[0][t] != 0.f) || (sw[1][t] != 0.f) || (sw[2][t] != 0.f);
        const unsigned long long m = __ballot(act);
        if (act) rows[__popcll(m & ((1ull << t) - 1ull))] = t;
        if (t == 0) s_nr = (int)__popcll(m);
    }
    __syncthreads();
    const int nr = s_nr;

    float a0x=0,a0y=0,a0z=0,a0w=0, a1x=0,a1y=0,a1z=0,a1w=0, a2x=0,a2y=0,a2z=0,a2w=0;
    const float* base = att + (size_t)b * N_ * N_ + (size_t)n0 * N_ + t * 4;
#pragma unroll 2
    for (int i = 0; i < nr; ++i) {
        const int r = rows[i];
        const float x0 = sw[0][r], x1 = sw[1][r], x2 = sw[2][r];
        const float4 v = *(const float4*)(base + (size_t)r * N_);
        a0x += x0*v.x; a0y += x0*v.y; a0z += x0*v.z; a0w += x0*v.w;
        a1x += x1*v.x; a1y += x1*v.y; a1z += x1*v.z; a1w += x1*v.w;
        a2x += x2*v.x; a2y += x2*v.y; a2z += x2*v.z; a2w += x2*v.w;
    }
    float* hp = Hpart + (size_t)(b * CH2_ + c) * 3 * N_ + t * 4;
    *(float4*)(hp)          = make_float4(a0x, a0y, a0z, a0w);
    *(float4*)(hp + N_)     = make_float4(a1x, a1y, a1z, a1w);
    *(float4*)(hp + 2 * N_) = make_float4(a2x, a2y, a2z, a2w);
}

// ---------------------------------------------------------------------------
// K3: reduce Hyper partials, softmax stats, emit w[e][n] and gg[e][n]=H*Dv.
// grid=(3, B), block=256.  Everything register-resident per thread (4 cols).
// ---------------------------------------------------------------------------
__global__ __launch_bounds__(256) void k3_wgg(
    const float* __restrict__ Hpart, const float* __restrict__ Dv,
    float* __restrict__ wArr, float* __restrict__ ggArr)
{
    const int e = blockIdx.x, b = blockIdx.y;
    const int t = threadIdx.x;
    const int lane = t & 63, wv = t >> 6;
    __shared__ float sred[4];

    float4 acc = make_float4(0.f, 0.f, 0.f, 0.f);
    for (int c = 0; c < CH2_; ++c) {
        const float4 v = *(const float4*)(Hpart + ((size_t)(b * CH2_ + c) * 3 + e) * N_ + t * 4);
        acc.x += v.x; acc.y += v.y; acc.z += v.z; acc.w += v.w;
    }
    // block max
    float m = fmaxf(fmaxf(acc.x, acc.y), fmaxf(acc.z, acc.w));
#pragma unroll
    for (int off = 32; off > 0; off >>= 1) m = fmaxf(m, __shfl_xor(m, off));
    if (lane == 0) sred[wv] = m;
    __syncthreads();
    m = fmaxf(fmaxf(sred[0], sred[1]), fmaxf(sred[2], sred[3]));
    __syncthreads();
    // block sum of exp
    float z = __expf(acc.x - m) + __expf(acc.y - m) + __expf(acc.z - m) + __expf(acc.w - m);
    z = wsum(z);
    if (lane == 0) sred[wv] = z;
    __syncthreads();
    const float iZ = 1.f / (sred[0] + sred[1] + sred[2] + sred[3]);

    const float4 dv = *(const float4*)(Dv + b * N_ + t * 4);
    float4 w4 = make_float4(__expf(acc.x - m) * iZ, __expf(acc.y - m) * iZ,
                            __expf(acc.z - m) * iZ, __expf(acc.w - m) * iZ);
    float4 g4 = make_float4(acc.x * dv.x, acc.y * dv.y, acc.z * dv.z, acc.w * dv.w);
    *(float4*)(wArr  + ((size_t)(b * 3 + e)) * N_ + t * 4) = w4;
    *(float4*)(ggArr + ((size_t)(b * 3 + e)) * N_ + t * 4) = g4;
}

// ---------------------------------------------------------------------------
// K4: partial U,G over h.  grid=(CH4_, B), block=192 (192*4 = 768 cols).
// Streams 64 full contiguous h rows; hot loop = 6 LDS broadcasts + float4 +
// 24 FMA.  Writes partial[b][c][6][H] (u0,u1,u2,g0,g1,g2).
// ---------------------------------------------------------------------------
__global__ __launch_bounds__(192) void k4_part(
    const float* __restrict__ h, const float* __restrict__ wArr,
    const float* __restrict__ ggArr, float* __restrict__ UGpart)
{
    const int b = blockIdx.y, c = blockIdx.x;
    const int n0 = c * 64;
    const int t = threadIdx.x;
    __shared__ float sw[6][64];
    for (int i = t; i < 384; i += 192) {
        const int s = i >> 6, r = i & 63;
        sw[s][r] = (s < 3) ? wArr[((size_t)(b * 3 + s)) * N_ + n0 + r]
                           : ggArr[((size_t)(b * 3 + s - 3)) * N_ + n0 + r];
    }
    __syncthreads();

    float u0x=0,u0y=0,u0z=0,u0w=0, u1x=0,u1y=0,u1z=0,u1w=0, u2x=0,u2y=0,u2z=0,u2w=0;
    float g0x=0,g0y=0,g0z=0,g0w=0, g1x=0,g1y=0,g1z=0,g1w=0, g2x=0,g2y=0,g2z=0,g2w=0;
    const float* base = h + (size_t)b * N_ * H_ + (size_t)n0 * H_ + t * 4;
#pragma unroll 4
    for (int r = 0; r < 64; ++r) {
        const float4 v = *(const float4*)(base + (size_t)r * H_);
        const float w0 = sw[0][r], w1 = sw[1][r], w2 = sw[2][r];
        const float g0 = sw[3][r], g1 = sw[4][r], g2 = sw[5][r];
        u0x += w0*v.x; u0y += w0*v.y; u0z += w0*v.z; u0w += w0*v.w;
        u1x += w1*v.x; u1y += w1*v.y; u1z += w1*v.z; u1w += w1*v.w;
        u2x += w2*v.x; u2y += w2*v.y; u2z += w2*v.z; u2w += w2*v.w;
        g0x += g0*v.x; g0y += g0*v.y; g0z += g0*v.z; g0w += g0*v.w;
        g1x += g1*v.x; g1y += g1*v.y; g1z += g1*v.z; g1w += g1*v.w;
        g2x += g2*v.x; g2y += g2*v.y; g2z += g2*v.z; g2w += g2*v.w;
    }
    float* up = UGpart + (size_t)(b * CH4_ + c) * 6 * H_ + t * 4;
    *(float4*)(up)          = make_float4(u0x, u0y, u0z, u0w);
    *(float4*)(up + H_)     = make_float4(u1x, u1y, u1z, u1w);
    *(float4*)(up + 2*H_)   = make_float4(u2x, u2y, u2z, u2w);
    *(float4*)(up + 3*H_)   = make_float4(g0x, g0y, g0z, g0w);
    *(float4*)(up + 4*H_)   = make_float4(g1x, g1y, g1z, g1w);
    *(float4*)(up + 5*H_)   = make_float4(g2x, g2y, g2z, g2w);
}

// ---------------------------------------------------------------------------
// K4b: reduce U/G partials.  144 blocks x 256, one float4 output per thread.
// ---------------------------------------------------------------------------
__global__ __launch_bounds__(256) void k4b_red(
    const float* __restrict__ UGpart, float* __restrict__ U, float* __restrict__ G)
{
    const int gid = blockIdx.x * 256 + threadIdx.x;   // 36864 threads
    const int b = gid / 1152;            // 6*768/4
    const int rem = gid % 1152;
    const int s = rem / 192;
    const int col = (rem % 192) * 4;

    float4 acc = make_float4(0.f, 0.f, 0.f, 0.f);
    for (int c = 0; c < CH4_; ++c) {
        const float4 v = *(const float4*)(UGpart + (size_t)(b * CH4_ + c) * 6 * H_ + s * H_ + col);
        acc.x += v.x; acc.y += v.y; acc.z += v.z; acc.w += v.w;
    }
    if (s < 3) *(float4*)(U + ((size_t)(b * 3 + s)) * H_ + col) = acc;
    else       *(float4*)(G + ((size_t)(b * 3 + s - 3)) * H_ + col) = acc;
}

// ---------------------------------------------------------------------------
// K5: finalize.  grid=B, block=256.
// ---------------------------------------------------------------------------
__global__ __launch_bounds__(256) void k5_fin(
    const float* __restrict__ U, const float* __restrict__ G,
    const float* __restrict__ De, const float* __restrict__ Dv,
    const float* __restrict__ aind, const float* __restrict__ bind,
    const float* __restrict__ speak_all,
    const float* __restrict__ W_w, const float* __restrict__ W_b,
    const float* __restrict__ S_w, const float* __restrict__ S_b,
    float* __restrict__ out)
{
    const int b = blockIdx.x, tid = threadIdx.x;
    const int lane = tid & 63, wv = tid >> 6;
    __shared__ float sKh[3 * H_];
    __shared__ float sscore[N_];
    __shared__ float sred[16];
    __shared__ int sidx[4];

    const float* Ub = U + (size_t)b * 3 * H_;
    const float* Gb = G + (size_t)b * 3 * H_;

    float p0 = 0.f, p1 = 0.f, p2 = 0.f;
    for (int j = tid; j < H_; j += 256) {
        const float ww = W_w[j];
        p0 += Ub[j] * ww; p1 += Ub[H_ + j] * ww; p2 += Ub[2 * H_ + j] * ww;
    }
    p0 = wsum(p0); p1 = wsum(p1); p2 = wsum(p2);
    if (lane == 0) { sred[wv * 3 + 0] = p0; sred[wv * 3 + 1] = p1; sred[wv * 3 + 2] = p2; }
    __syncthreads();
    const float wb = W_b[0];
    const float l0 = sred[0] + sred[3] + sred[6] + sred[9]  + wb;
    const float l1 = sred[1] + sred[4] + sred[7] + sred[10] + wb;
    const float l2 = sred[2] + sred[5] + sred[8] + sred[11] + wb;
    const float mx = fmaxf(l0, fmaxf(l1, l2));
    const float e0 = expf(l0 - mx), e1 = expf(l1 - mx), e2 = expf(l2 - mx);
    const float inv = 1.f / (e0 + e1 + e2);
    const float wd0 = e0 * inv * De[b * 3 + 0];
    const float wd1 = e1 * inv * De[b * 3 + 1];
    const float wd2 = e2 * inv * De[b * 3 + 2];

    for (int j = tid; j < H_; j += 256) {
        sKh[j]          = wd0 * Gb[j];
        sKh[H_ + j]     = wd1 * Gb[H_ + j];
        sKh[2 * H_ + j] = wd2 * Gb[2 * H_ + j];
    }
    __syncthreads();

    float q0 = 0.f, q1 = 0.f, q2 = 0.f;
    for (int j = tid; j < H_; j += 256) {
        const float sw2 = S_w[j];
        q0 += sKh[j] * sw2; q1 += sKh[H_ + j] * sw2; q2 += sKh[2 * H_ + j] * sw2;
    }
    q0 = wsum(q0); q1 = wsum(q1); q2 = wsum(q2);
    if (lane == 0) { sred[wv * 3 + 0] = q0; sred[wv * 3 + 1] = q1; sred[wv * 3 + 2] = q2; }
    __syncthreads();
    q0 = sred[0] + sred[3] + sred[6] + sred[9];
    q1 = sred[1] + sred[4] + sred[7] + sred[10];
    q2 = sred[2] + sred[5] + sred[8] + sred[11];

    const float sb0 = S_b[0];
    const float* av = aind + b * N_;
    const float* bv2 = bind + b * N_;
    const float* dv = Dv + b * N_;
    const float* sv = speak_all + (size_t)b * 3 * N_;
    for (int n = tid; n < N_; n += 256)
        sscore[n] = dv[n] * (av[n] * q0 + bv2[n] * q1 + sv[n] * q2) + sb0;
    __syncthreads();

    int r0;
    {
        float best = -INFINITY; int bi = N_;
        for (int n = tid; n < N_; n += 256) {
            const float s = sscore[n];
            if (s > best || (s == best && n < bi)) { best = s; bi = n; }
        }
#pragma unroll
        for (int off = 32; off > 0; off >>= 1) {
            const float ov = __shfl_xor(best, off); const int oi = __shfl_xor(bi, off);
            if (ov > best || (ov == best && oi < bi)) { best = ov; bi = oi; }
        }
        if (lane == 0) { sred[wv] = best; sidx[wv] = bi; }
        __syncthreads();
        float v = -INFINITY; int i = N_;
        for (int k = 0; k < 4; ++k)
            if (sred[k] > v || (sred[k] == v && sidx[k] < i)) { v = sred[k]; i = sidx[k]; }
        r0 = i;
    }
    __syncthreads();
    int r1;
    {
        float best = -INFINITY; int bi = N_;
        for (int n = tid; n < N_; n += 256) {
            if (n == r0) continue;
            const float s = sscore[n];
            if (s > best || (s == best && n < bi)) { best = s; bi = n; }
        }
#pragma unroll
        for (int off = 32; off > 0; off >>= 1) {
            const float ov = __shfl_xor(best, off); const int oi = __shfl_xor(bi, off);
            if (ov > best || (ov == best && oi < bi)) { best = ov; bi = oi; }
        }
        if (lane == 0) { sred[wv] = best; sidx[wv] = bi; }
        __syncthreads();
        float v = -INFINITY; int i = N_;
        for (int k = 0; k < 4; ++k)
            if (sred[k] > v || (sred[k] == v && sidx[k] < i)) { v = sred[k]; i = sidx[k]; }
        r1 = i;
    }

    float* ob = out + (size_t)b * 2 * H_;
    {
        const float d = dv[r0], wa = av[r0], wbn = bv2[r0], wsv = sv[r0];
        for (int j = tid; j < H_; j += 256)
            ob[j] = d * (wa * sKh[j] + wbn * sKh[H_ + j] + wsv * sKh[2 * H_ + j]);
    }
    {
        const float d = dv[r1], wa = av[r1], wbn = bv2[r1], wsv = sv[r1];
        for (int j = tid; j < H_; j += 256)
            ob[H_ + j] = d * (wa * sKh[j] + wbn * sKh[H_ + j] + wsv * sKh[2 * H_ + j]);
    }
}

extern "C" void kernel_launch(void* const* d_in, const int* in_sizes, int n_in,
                              void* d_out, int out_size, void* d_ws, size_t ws_size,
                              hipStream_t stream)
{
    const float* h         = (const float*)d_in[0];   // (B,N,H)
    const float* att       = (const float*)d_in[1];   // (B,1,N,N)
    const int*   a_idx     = (const int*)d_in[2];     // (B,8)
    const int*   b_idx     = (const int*)d_in[3];     // (B,8)
    const float* speak_all = (const float*)d_in[5];   // (B,3,N)
    const float* W_w       = (const float*)d_in[6];   // (1,H)
    const float* W_b       = (const float*)d_in[7];   // (1,)
    const float* S_w       = (const float*)d_in[8];   // (1,H)
    const float* S_b       = (const float*)d_in[9];   // (1,)
    float* out = (float*)d_out;

    // workspace (floats); every region fully written before read
    float* ws     = (float*)d_ws;
    float* aind   = ws;                          // B*N
    float* bind   = aind + B_ * N_;              // B*N
    float* Dv     = bind + B_ * N_;              // B*N
    float* De     = Dv + B_ * N_;                // pad 128
    float* Hpart  = De + 128;                    // B*CH2_*3*N
    float* wArr   = Hpart + B_ * CH2_ * 3 * N_;  // B*3*N
    float* ggArr  = wArr + B_ * 3 * N_;          // B*3*N
    float* UGpart = ggArr + B_ * 3 * N_;         // B*CH4_*6*H
    float* U      = UGpart + B_ * CH4_ * 6 * H_; // B*3*H
    float* G      = U + B_ * 3 * H_;             // B*3*H

    k1_ind<<<B_, 1024, 0, stream>>>(att, a_idx, b_idx, speak_all, aind, bind, Dv, De);
    k2_part<<<dim3(CH2_, B_), 256, 0, stream>>>(att, aind, bind, speak_all, Hpart);
    k3_wgg<<<dim3(3, B_), 256, 0, stream>>>(Hpart, Dv, wArr, ggArr);
    k4_part<<<dim3(CH4_, B_), 192, 0, stream>>>(h, wArr, ggArr, UGpart);
    k4b_red<<<144, 256, 0, stream>>>(UGpart, U, G);
    k5_fin<<<B_, 256, 0, stream>>>(U, G, De, Dv, aind, bind, speak_all, W_w, W_b, S_w, S_b, out);
}